// Round 10
// baseline (345.876 us; speedup 1.0000x reference)
//
#include <hip/hip_runtime.h>

#define BATCH 32
#define DIM 4096
#define NH 32
#define NKV 8
#define HD 128
#define CTX 4096
#define NEWT 4095
#define CHUNK 512
#define NCH 8
#define NSPLIT 32
#define KCH (DIM / NSPLIT)   // 128
#define NQKV 6144            // 4096 q + 1024 k + 1024 v
#define SM_SCALE 0.08838834764831845f  // 1/sqrt(128)

// ---- transpose (32, N) -> (N, 32) ----
__global__ __launch_bounds__(256) void transpose32(
    const float* __restrict__ src, float* __restrict__ dst, int N) {
  __shared__ float tile[32][33];
  int n0 = blockIdx.x * 32;
  int tn = threadIdx.x & 31;
  int tb = threadIdx.x >> 5;   // 0..7
#pragma unroll
  for (int bb = 0; bb < 4; ++bb) {
    int b = bb * 8 + tb;
    tile[b][tn] = src[(size_t)b * N + n0 + tn];
  }
  __syncthreads();
  int wb = threadIdx.x & 31;
  int wn = threadIdx.x >> 5;   // 0..7
#pragma unroll
  for (int nn = 0; nn < 4; ++nn) {
    int n = nn * 8 + wn;
    dst[(size_t)(n0 + n) * 32 + wb] = tile[wb][n];
  }
}

// ---- stage 1: partial GEMM, A transposed, 2 columns per thread ----
__global__ __launch_bounds__(256, 4) void gemm_qkv_part(
    const float* __restrict__ AT, const float* __restrict__ wq,
    const float* __restrict__ wk, const float* __restrict__ wv,
    float* __restrict__ part) {
  int bx = blockIdx.x;                      // 0..11, 512 cols each
  int sy = blockIdx.y;                      // 0..31
  int cg = bx * 512 + threadIdx.x * 2;      // global col pair base
  const float* W; int cw, Nw;
  if (bx < 8)       { W = wq; cw = cg;        Nw = 4096; }
  else if (bx < 10) { W = wk; cw = cg - 4096; Nw = 1024; }
  else              { W = wv; cw = cg - 5120; Nw = 1024; }
  int k0 = sy * KCH;
  float acc0[BATCH], acc1[BATCH];
#pragma unroll
  for (int b = 0; b < BATCH; ++b) { acc0[b] = 0.f; acc1[b] = 0.f; }
  const float* Wp = W + (size_t)k0 * Nw + cw;
  const float* ATp = AT + (size_t)k0 * 32;
#pragma unroll 2
  for (int k = 0; k < KCH; ++k) {
    float2 wv2 = *(const float2*)(Wp + (size_t)k * Nw);
    const float4* Ak = (const float4*)(ATp + k * 32);   // uniform -> s_load
#pragma unroll
    for (int q8 = 0; q8 < 8; ++q8) {
      float4 av = Ak[q8];
      acc0[q8 * 4 + 0] += av.x * wv2.x;  acc1[q8 * 4 + 0] += av.x * wv2.y;
      acc0[q8 * 4 + 1] += av.y * wv2.x;  acc1[q8 * 4 + 1] += av.y * wv2.y;
      acc0[q8 * 4 + 2] += av.z * wv2.x;  acc1[q8 * 4 + 2] += av.z * wv2.y;
      acc0[q8 * 4 + 3] += av.w * wv2.x;  acc1[q8 * 4 + 3] += av.w * wv2.y;
    }
  }
#pragma unroll
  for (int b = 0; b < BATCH; ++b)
    *(float2*)&part[((size_t)sy * BATCH + b) * NQKV + cg] = make_float2(acc0[b], acc1[b]);
}

// ---- stage 2: reduce partials + RoPE ----
__global__ __launch_bounds__(256) void qkv_reduce_rope(
    const float* __restrict__ part, const float* __restrict__ cos_t,
    const float* __restrict__ sin_t, float* __restrict__ q,
    float* __restrict__ k, float* __restrict__ v) {
  int idx = blockIdx.x * 256 + threadIdx.x;
  int b = idx / 3072, c2 = idx - b * 3072;
  int c = c2 * 2;
  float s0 = 0.f, s1 = 0.f;
#pragma unroll 8
  for (int s = 0; s < NSPLIT; ++s) {
    float2 pv = *(const float2*)&part[((size_t)s * BATCH + b) * NQKV + c];
    s0 += pv.x; s1 += pv.y;
  }
  if (c < 4096) {
    int p = (c & 127) >> 1;
    float cc = cos_t[p], ss = sin_t[p];
    q[b * 4096 + c]     = s0 * cc - s1 * ss;
    q[b * 4096 + c + 1] = s0 * ss + s1 * cc;
  } else if (c < 5120) {
    int c0 = c - 4096;
    int p = (c0 & 127) >> 1;
    float cc = cos_t[p], ss = sin_t[p];
    k[b * 1024 + c0]     = s0 * cc - s1 * ss;
    k[b * 1024 + c0 + 1] = s0 * ss + s1 * cc;
  } else {
    int c0 = c - 5120;
    v[b * 1024 + c0]     = s0;
    v[b * 1024 + c0 + 1] = s1;
  }
}

// ---- flash-decode partial: one block per (b, kv_head, chunk) ----
__global__ __launch_bounds__(256, 2) void attn_kernel(
    const float* __restrict__ q,
    const float* __restrict__ kcache,
    const float* __restrict__ vcache,
    const float* __restrict__ knew,
    const float* __restrict__ vnew,
    float* __restrict__ pm, float* __restrict__ pl,
    float* __restrict__ pacc) {
  __shared__ float sc[4 * CHUNK];   // 8 KB
  __shared__ float sml[8];
  int blk = blockIdx.x;
  int c = blk & 7, h = (blk >> 3) & 7, b = blk >> 6;
  int tid = threadIdx.x;
  int wave = tid >> 6, sub = tid & 63;
  int t_base = c * CHUNK;

  // phase 1: scores
  int tg = tid >> 4;    // 0..15 t-rows per pass
  int lig = tid & 15;   // covers 8 d's
  float qreg[4][8];
#pragma unroll
  for (int r = 0; r < 4; ++r)
#pragma unroll
    for (int j = 0; j < 8; ++j)
      qreg[r][j] = q[b * (NH * HD) + (h * 4 + r) * HD + lig * 8 + j];

  const float* kbase = kcache + ((size_t)b * CTX * NKV + h) * HD;
  const float* knrow = knew + (b * NKV + h) * HD;
  for (int t0 = 0; t0 < CHUNK; t0 += 16) {
    int tl = t0 + tg;
    int t = t_base + tl;
    const float* krow = (t < NEWT) ? (kbase + (size_t)t * (NKV * HD)) : knrow;
    float4 ka = *(const float4*)(krow + lig * 8);
    float4 kb = *(const float4*)(krow + lig * 8 + 4);
#pragma unroll
    for (int r = 0; r < 4; ++r) {
      float part = ka.x * qreg[r][0] + ka.y * qreg[r][1] + ka.z * qreg[r][2] + ka.w * qreg[r][3]
                 + kb.x * qreg[r][4] + kb.y * qreg[r][5] + kb.z * qreg[r][6] + kb.w * qreg[r][7];
#pragma unroll
      for (int off = 8; off >= 1; off >>= 1)
        part += __shfl_xor(part, off);
      if (lig == 0) sc[r * CHUNK + tl] = part * SM_SCALE;
    }
  }
  __syncthreads();

  // chunk softmax (unnormalized), wave r handles row r
  {
    int r = wave;
    float m = -1e30f;
    for (int i = sub; i < CHUNK; i += 64) m = fmaxf(m, sc[r * CHUNK + i]);
#pragma unroll
    for (int off = 32; off >= 1; off >>= 1) m = fmaxf(m, __shfl_xor(m, off));
    float ssum = 0.f;
    for (int i = sub; i < CHUNK; i += 64) {
      float pv = __expf(sc[r * CHUNK + i] - m);
      sc[r * CHUNK + i] = pv;
      ssum += pv;
    }
#pragma unroll
    for (int off = 32; off >= 1; off >>= 1) ssum += __shfl_xor(ssum, off);
    if (sub == 0) { sml[r] = m; sml[4 + r] = ssum; }
  }
  __syncthreads();
  if (tid < 4) {
    pm[blk * 4 + tid] = sml[tid];
    pl[blk * 4 + tid] = sml[4 + tid];
  }

  // phase 2: acc[r][d] = sum_t p[r][t] * V[t][d]
  int dg = tid & 31;
  int tg2 = tid >> 5;   // 0..7
  float4 acc[4];
#pragma unroll
  for (int r = 0; r < 4; ++r) acc[r] = make_float4(0.f, 0.f, 0.f, 0.f);
  const float* vbase = vcache + ((size_t)b * CTX * NKV + h) * HD;
  const float* vnrow = vnew + (b * NKV + h) * HD;
  for (int t0 = 0; t0 < CHUNK; t0 += 16) {
    int tla = t0 + tg2, tlb = t0 + tg2 + 8;
    int ta = t_base + tla, tb = t_base + tlb;
    const float* vra = (ta < NEWT) ? (vbase + (size_t)ta * (NKV * HD)) : vnrow;
    const float* vrb = (tb < NEWT) ? (vbase + (size_t)tb * (NKV * HD)) : vnrow;
    float4 va = *(const float4*)(vra + dg * 4);
    float4 vb = *(const float4*)(vrb + dg * 4);
#pragma unroll
    for (int r = 0; r < 4; ++r) {
      float pa = sc[r * CHUNK + tla];
      float pb = sc[r * CHUNK + tlb];
      acc[r].x += pa * va.x + pb * vb.x;
      acc[r].y += pa * va.y + pb * vb.y;
      acc[r].z += pa * va.z + pb * vb.z;
      acc[r].w += pa * va.w + pb * vb.w;
    }
  }
#pragma unroll
  for (int r = 0; r < 4; ++r) {
    acc[r].x += __shfl_xor(acc[r].x, 32);
    acc[r].y += __shfl_xor(acc[r].y, 32);
    acc[r].z += __shfl_xor(acc[r].z, 32);
    acc[r].w += __shfl_xor(acc[r].w, 32);
  }
  __syncthreads();
  if (sub < 32) {
#pragma unroll
    for (int r = 0; r < 4; ++r)
      *(float4*)&sc[wave * 512 + r * 128 + dg * 4] = acc[r];
  }
  __syncthreads();
#pragma unroll
  for (int rr = 0; rr < 2; ++rr) {
    int idx = tid + rr * 256;
    int r = idx >> 7, d = idx & 127;
    float s = sc[r * 128 + d] + sc[512 + r * 128 + d]
            + sc[1024 + r * 128 + d] + sc[1536 + r * 128 + d];
    pacc[(size_t)blk * 512 + r * 128 + d] = s;
  }
}

__global__ __launch_bounds__(256) void combine_kernel(
    const float* __restrict__ pm, const float* __restrict__ pl,
    const float* __restrict__ pacc, float* __restrict__ outa) {
  int idx = blockIdx.x * 256 + threadIdx.x;
  int d = idx & 127, r = (idx >> 7) & 3, h = (idx >> 9) & 7, b = idx >> 12;
  int base = (b * 8 + h) * 8;
  float M = -1e30f;
#pragma unroll
  for (int c = 0; c < NCH; ++c) M = fmaxf(M, pm[(base + c) * 4 + r]);
  float num = 0.f, den = 0.f;
#pragma unroll
  for (int c = 0; c < NCH; ++c) {
    float w = __expf(pm[(base + c) * 4 + r] - M);
    den += w * pl[(base + c) * 4 + r];
    num += w * pacc[(size_t)(base + c) * 512 + r * 128 + d];
  }
  outa[b * (NH * HD) + (h * 4 + r) * HD + d] = num / den;
}

// ---- wo projection, A transposed, 2 columns per thread ----
__global__ __launch_bounds__(256, 4) void gemm_wo_part(
    const float* __restrict__ AT, const float* __restrict__ W,
    float* __restrict__ part) {
  int cg = blockIdx.x * 512 + threadIdx.x * 2;   // 8 bx blocks
  int sy = blockIdx.y;
  int k0 = sy * KCH;
  float acc0[BATCH], acc1[BATCH];
#pragma unroll
  for (int b = 0; b < BATCH; ++b) { acc0[b] = 0.f; acc1[b] = 0.f; }
  const float* Wp = W + (size_t)k0 * DIM + cg;
  const float* ATp = AT + (size_t)k0 * 32;
#pragma unroll 2
  for (int k = 0; k < KCH; ++k) {
    float2 wv2 = *(const float2*)(Wp + (size_t)k * DIM);
    const float4* Ak = (const float4*)(ATp + k * 32);
#pragma unroll
    for (int q8 = 0; q8 < 8; ++q8) {
      float4 av = Ak[q8];
      acc0[q8 * 4 + 0] += av.x * wv2.x;  acc1[q8 * 4 + 0] += av.x * wv2.y;
      acc0[q8 * 4 + 1] += av.y * wv2.x;  acc1[q8 * 4 + 1] += av.y * wv2.y;
      acc0[q8 * 4 + 2] += av.z * wv2.x;  acc1[q8 * 4 + 2] += av.z * wv2.y;
      acc0[q8 * 4 + 3] += av.w * wv2.x;  acc1[q8 * 4 + 3] += av.w * wv2.y;
    }
  }
#pragma unroll
  for (int b = 0; b < BATCH; ++b)
    *(float2*)&part[((size_t)sy * BATCH + b) * DIM + cg] = make_float2(acc0[b], acc1[b]);
}

__global__ __launch_bounds__(256) void wo_reduce(
    const float* __restrict__ part, float* __restrict__ out) {
  int idx = blockIdx.x * 256 + threadIdx.x;
  int b = idx >> 11, c2 = idx & 2047;
  int c = c2 * 2;
  float s0 = 0.f, s1 = 0.f;
#pragma unroll 8
  for (int s = 0; s < NSPLIT; ++s) {
    float2 pv = *(const float2*)&part[((size_t)s * BATCH + b) * DIM + c];
    s0 += pv.x; s1 += pv.y;
  }
  out[b * DIM + c]     = s0;
  out[b * DIM + c + 1] = s1;
}

extern "C" void kernel_launch(void* const* d_in, const int* in_sizes, int n_in,
                              void* d_out, int out_size, void* d_ws, size_t ws_size,
                              hipStream_t stream) {
  const float* x  = (const float*)d_in[0];
  const float* wq = (const float*)d_in[1];
  const float* wk = (const float*)d_in[2];
  const float* wv = (const float*)d_in[3];
  const float* wo = (const float*)d_in[4];
  const float* ck = (const float*)d_in[5];
  const float* cv = (const float*)d_in[6];
  const float* fc = (const float*)d_in[7];
  const float* fs = (const float*)d_in[8];
  float* out = (float*)d_out;

  float* ws    = (float*)d_ws;
  float* ws_q  = ws;               // 131072
  float* ws_k  = ws + 131072;      // 32768
  float* ws_v  = ws + 163840;      // 32768
  float* ws_a  = ws + 196608;      // 131072
  float* pm    = ws + 327680;      // 8192
  float* pl    = ws + 335872;      // 8192
  float* pacc  = ws + 344064;      // 1048576
  float* partq = ws + 1392640;     // 6291456
  float* parto = ws + 7684096;     // 4194304
  float* xT    = ws + 11878400;    // 131072
  float* aT    = ws + 12009472;    // 131072

  transpose32<<<128, 256, 0, stream>>>(x, xT, DIM);
  gemm_qkv_part<<<dim3(12, NSPLIT), 256, 0, stream>>>(xT, wq, wk, wv, partq);
  qkv_reduce_rope<<<384, 256, 0, stream>>>(partq, fc, fs, ws_q, ws_k, ws_v);

  attn_kernel<<<BATCH * NKV * NCH, 256, 0, stream>>>(ws_q, ck, cv, ws_k, ws_v, pm, pl, pacc);
  combine_kernel<<<512, 256, 0, stream>>>(pm, pl, pacc, ws_a);

  transpose32<<<128, 256, 0, stream>>>(ws_a, aT, DIM);
  gemm_wo_part<<<dim3(8, NSPLIT), 256, 0, stream>>>(aT, wo, parto);
  wo_reduce<<<256, 256, 0, stream>>>(parto, out);
}

// Round 11
// 266.466 us; speedup vs baseline: 1.2980x; 1.2980x over previous
//
#include <hip/hip_runtime.h>
#include <hip/hip_bf16.h>

#define BATCH 32
#define DIM 4096
#define NH 32
#define NKV 8
#define HD 128
#define CTX 4096
#define NEWT 4095
#define CHUNK 512
#define NCH 8
#define QS 8                 // k-split for MFMA GEMMs
#define NQKV 6144
#define SM_SCALE 0.08838834764831845f  // 1/sqrt(128)

typedef __attribute__((ext_vector_type(8))) short bf16x8;
typedef __attribute__((ext_vector_type(4))) float f32x4;

__device__ inline unsigned short f2bf(float f) {
  union { __hip_bfloat16 h; unsigned short s; } u;
  u.h = __float2bfloat16(f);
  return u.s;
}
__device__ inline float bf2f(unsigned short s) {
  union { unsigned int u; float f; } v;
  v.u = ((unsigned int)s) << 16;
  return v.f;
}

// ---- fp32 -> (hi, lo) bf16 ----
__global__ __launch_bounds__(256) void cvt_hl(
    const float* __restrict__ src, unsigned short* __restrict__ hi,
    unsigned short* __restrict__ lo, int n) {
  int i = blockIdx.x * 256 + threadIdx.x;
  if (i < n) {
    float f = src[i];
    unsigned short h = f2bf(f);
    hi[i] = h;
    lo[i] = f2bf(f - bf2f(h));
  }
}

// ---- qkv GEMM via split-bf16 MFMA. C[32 x 6144] = x[32 x 4096] @ Wcat ----
// wave = one 16-col tile; block = 4 tiles; grid.y = k-split (512 k each).
__global__ __launch_bounds__(256) void gemm_qkv_mfma(
    const unsigned short* __restrict__ xhi, const unsigned short* __restrict__ xlo,
    const float* __restrict__ wq, const float* __restrict__ wk,
    const float* __restrict__ wv, float* __restrict__ part) {
  int w = threadIdx.x >> 6, l = threadIdx.x & 63;
  int lc = l & 15, grp = l >> 4;
  int c = (blockIdx.x * 4 + w) * 16 + lc;       // global col 0..6143
  int sy = blockIdx.y;
  const float* W; int cw, Nw;
  if (c < 4096)      { W = wq; cw = c;        Nw = 4096; }
  else if (c < 5120) { W = wk; cw = c - 4096; Nw = 1024; }
  else               { W = wv; cw = c - 5120; Nw = 1024; }
  f32x4 acc0 = {0.f, 0.f, 0.f, 0.f}, acc1 = {0.f, 0.f, 0.f, 0.f};
  for (int ks = 0; ks < 16; ++ks) {
    int K0 = sy * 512 + ks * 32;
    int ak = K0 + grp * 8;
    bf16x8 a0h = *(const bf16x8*)(xhi + (size_t)lc * DIM + ak);
    bf16x8 a0l = *(const bf16x8*)(xlo + (size_t)lc * DIM + ak);
    bf16x8 a1h = *(const bf16x8*)(xhi + (size_t)(16 + lc) * DIM + ak);
    bf16x8 a1l = *(const bf16x8*)(xlo + (size_t)(16 + lc) * DIM + ak);
    float wvv[8];
#pragma unroll
    for (int j = 0; j < 8; ++j)
      wvv[j] = W[(size_t)(ak + j) * Nw + cw];
    bf16x8 bh, bl;
#pragma unroll
    for (int j = 0; j < 8; ++j) {
      unsigned short h = f2bf(wvv[j]);
      bh[j] = (short)h;
      bl[j] = (short)f2bf(wvv[j] - bf2f(h));
    }
    acc0 = __builtin_amdgcn_mfma_f32_16x16x32_bf16(a0h, bh, acc0, 0, 0, 0);
    acc0 = __builtin_amdgcn_mfma_f32_16x16x32_bf16(a0h, bl, acc0, 0, 0, 0);
    acc0 = __builtin_amdgcn_mfma_f32_16x16x32_bf16(a0l, bh, acc0, 0, 0, 0);
    acc1 = __builtin_amdgcn_mfma_f32_16x16x32_bf16(a1h, bh, acc1, 0, 0, 0);
    acc1 = __builtin_amdgcn_mfma_f32_16x16x32_bf16(a1h, bl, acc1, 0, 0, 0);
    acc1 = __builtin_amdgcn_mfma_f32_16x16x32_bf16(a1l, bh, acc1, 0, 0, 0);
  }
#pragma unroll
  for (int i = 0; i < 4; ++i) {
    int b0 = grp * 4 + i;                         // C row = (lane>>4)*4 + reg
    part[((size_t)sy * BATCH + b0) * NQKV + c] = acc0[i];
    part[((size_t)sy * BATCH + 16 + b0) * NQKV + c] = acc1[i];
  }
}

// ---- wo GEMM, same scheme. C[32 x 4096] = a[32 x 4096] @ wo ----
__global__ __launch_bounds__(256) void gemm_wo_mfma(
    const unsigned short* __restrict__ ahi, const unsigned short* __restrict__ alo,
    const float* __restrict__ W, float* __restrict__ part) {
  int w = threadIdx.x >> 6, l = threadIdx.x & 63;
  int lc = l & 15, grp = l >> 4;
  int c = (blockIdx.x * 4 + w) * 16 + lc;       // 0..4095
  int sy = blockIdx.y;
  f32x4 acc0 = {0.f, 0.f, 0.f, 0.f}, acc1 = {0.f, 0.f, 0.f, 0.f};
  for (int ks = 0; ks < 16; ++ks) {
    int K0 = sy * 512 + ks * 32;
    int ak = K0 + grp * 8;
    bf16x8 a0h = *(const bf16x8*)(ahi + (size_t)lc * DIM + ak);
    bf16x8 a0l = *(const bf16x8*)(alo + (size_t)lc * DIM + ak);
    bf16x8 a1h = *(const bf16x8*)(ahi + (size_t)(16 + lc) * DIM + ak);
    bf16x8 a1l = *(const bf16x8*)(alo + (size_t)(16 + lc) * DIM + ak);
    float wvv[8];
#pragma unroll
    for (int j = 0; j < 8; ++j)
      wvv[j] = W[(size_t)(ak + j) * DIM + c];
    bf16x8 bh, bl;
#pragma unroll
    for (int j = 0; j < 8; ++j) {
      unsigned short h = f2bf(wvv[j]);
      bh[j] = (short)h;
      bl[j] = (short)f2bf(wvv[j] - bf2f(h));
    }
    acc0 = __builtin_amdgcn_mfma_f32_16x16x32_bf16(a0h, bh, acc0, 0, 0, 0);
    acc0 = __builtin_amdgcn_mfma_f32_16x16x32_bf16(a0h, bl, acc0, 0, 0, 0);
    acc0 = __builtin_amdgcn_mfma_f32_16x16x32_bf16(a0l, bh, acc0, 0, 0, 0);
    acc1 = __builtin_amdgcn_mfma_f32_16x16x32_bf16(a1h, bh, acc1, 0, 0, 0);
    acc1 = __builtin_amdgcn_mfma_f32_16x16x32_bf16(a1h, bl, acc1, 0, 0, 0);
    acc1 = __builtin_amdgcn_mfma_f32_16x16x32_bf16(a1l, bh, acc1, 0, 0, 0);
  }
#pragma unroll
  for (int i = 0; i < 4; ++i) {
    int b0 = grp * 4 + i;
    part[((size_t)sy * BATCH + b0) * DIM + c] = acc0[i];
    part[((size_t)sy * BATCH + 16 + b0) * DIM + c] = acc1[i];
  }
}

// ---- reduce qkv partials + RoPE ----
__global__ __launch_bounds__(256) void qkv_reduce_rope(
    const float* __restrict__ part, const float* __restrict__ cos_t,
    const float* __restrict__ sin_t, float* __restrict__ q,
    float* __restrict__ k, float* __restrict__ v) {
  int idx = blockIdx.x * 256 + threadIdx.x;
  int b = idx / 3072, c2 = idx - b * 3072;
  int c = c2 * 2;
  float s0 = 0.f, s1 = 0.f;
#pragma unroll
  for (int s = 0; s < QS; ++s) {
    float2 pv = *(const float2*)&part[((size_t)s * BATCH + b) * NQKV + c];
    s0 += pv.x; s1 += pv.y;
  }
  if (c < 4096) {
    int p = (c & 127) >> 1;
    float cc = cos_t[p], ss = sin_t[p];
    q[b * 4096 + c]     = s0 * cc - s1 * ss;
    q[b * 4096 + c + 1] = s0 * ss + s1 * cc;
  } else if (c < 5120) {
    int c0 = c - 4096;
    int p = (c0 & 127) >> 1;
    float cc = cos_t[p], ss = sin_t[p];
    k[b * 1024 + c0]     = s0 * cc - s1 * ss;
    k[b * 1024 + c0 + 1] = s0 * ss + s1 * cc;
  } else {
    int c0 = c - 5120;
    v[b * 1024 + c0]     = s0;
    v[b * 1024 + c0 + 1] = s1;
  }
}

// ---- flash-decode partial: one block per (b, kv_head, chunk) ---- (R3-proven)
__global__ __launch_bounds__(256, 2) void attn_kernel(
    const float* __restrict__ q,
    const float* __restrict__ kcache,
    const float* __restrict__ vcache,
    const float* __restrict__ knew,
    const float* __restrict__ vnew,
    float* __restrict__ pm, float* __restrict__ pl,
    float* __restrict__ pacc) {
  __shared__ float sc[4 * CHUNK];
  __shared__ float sml[8];
  int blk = blockIdx.x;
  int c = blk & 7, h = (blk >> 3) & 7, b = blk >> 6;
  int tid = threadIdx.x;
  int wave = tid >> 6, sub = tid & 63;
  int t_base = c * CHUNK;

  int tg = tid >> 4;
  int lig = tid & 15;
  float qreg[4][8];
#pragma unroll
  for (int r = 0; r < 4; ++r)
#pragma unroll
    for (int j = 0; j < 8; ++j)
      qreg[r][j] = q[b * (NH * HD) + (h * 4 + r) * HD + lig * 8 + j];

  const float* kbase = kcache + ((size_t)b * CTX * NKV + h) * HD;
  const float* knrow = knew + (b * NKV + h) * HD;
  for (int t0 = 0; t0 < CHUNK; t0 += 16) {
    int tl = t0 + tg;
    int t = t_base + tl;
    const float* krow = (t < NEWT) ? (kbase + (size_t)t * (NKV * HD)) : knrow;
    float4 ka = *(const float4*)(krow + lig * 8);
    float4 kb = *(const float4*)(krow + lig * 8 + 4);
#pragma unroll
    for (int r = 0; r < 4; ++r) {
      float part = ka.x * qreg[r][0] + ka.y * qreg[r][1] + ka.z * qreg[r][2] + ka.w * qreg[r][3]
                 + kb.x * qreg[r][4] + kb.y * qreg[r][5] + kb.z * qreg[r][6] + kb.w * qreg[r][7];
#pragma unroll
      for (int off = 8; off >= 1; off >>= 1)
        part += __shfl_xor(part, off);
      if (lig == 0) sc[r * CHUNK + tl] = part * SM_SCALE;
    }
  }
  __syncthreads();

  {
    int r = wave;
    float m = -1e30f;
    for (int i = sub; i < CHUNK; i += 64) m = fmaxf(m, sc[r * CHUNK + i]);
#pragma unroll
    for (int off = 32; off >= 1; off >>= 1) m = fmaxf(m, __shfl_xor(m, off));
    float ssum = 0.f;
    for (int i = sub; i < CHUNK; i += 64) {
      float pv = __expf(sc[r * CHUNK + i] - m);
      sc[r * CHUNK + i] = pv;
      ssum += pv;
    }
#pragma unroll
    for (int off = 32; off >= 1; off >>= 1) ssum += __shfl_xor(ssum, off);
    if (sub == 0) { sml[r] = m; sml[4 + r] = ssum; }
  }
  __syncthreads();
  if (tid < 4) {
    pm[blk * 4 + tid] = sml[tid];
    pl[blk * 4 + tid] = sml[4 + tid];
  }

  int dg = tid & 31;
  int tg2 = tid >> 5;
  float4 acc[4];
#pragma unroll
  for (int r = 0; r < 4; ++r) acc[r] = make_float4(0.f, 0.f, 0.f, 0.f);
  const float* vbase = vcache + ((size_t)b * CTX * NKV + h) * HD;
  const float* vnrow = vnew + (b * NKV + h) * HD;
  for (int t0 = 0; t0 < CHUNK; t0 += 16) {
    int tla = t0 + tg2, tlb = t0 + tg2 + 8;
    int ta = t_base + tla, tb = t_base + tlb;
    const float* vra = (ta < NEWT) ? (vbase + (size_t)ta * (NKV * HD)) : vnrow;
    const float* vrb = (tb < NEWT) ? (vbase + (size_t)tb * (NKV * HD)) : vnrow;
    float4 va = *(const float4*)(vra + dg * 4);
    float4 vb = *(const float4*)(vrb + dg * 4);
#pragma unroll
    for (int r = 0; r < 4; ++r) {
      float pa = sc[r * CHUNK + tla];
      float pb = sc[r * CHUNK + tlb];
      acc[r].x += pa * va.x + pb * vb.x;
      acc[r].y += pa * va.y + pb * vb.y;
      acc[r].z += pa * va.z + pb * vb.z;
      acc[r].w += pa * va.w + pb * vb.w;
    }
  }
#pragma unroll
  for (int r = 0; r < 4; ++r) {
    acc[r].x += __shfl_xor(acc[r].x, 32);
    acc[r].y += __shfl_xor(acc[r].y, 32);
    acc[r].z += __shfl_xor(acc[r].z, 32);
    acc[r].w += __shfl_xor(acc[r].w, 32);
  }
  __syncthreads();
  if (sub < 32) {
#pragma unroll
    for (int r = 0; r < 4; ++r)
      *(float4*)&sc[wave * 512 + r * 128 + dg * 4] = acc[r];
  }
  __syncthreads();
#pragma unroll
  for (int rr = 0; rr < 2; ++rr) {
    int idx = tid + rr * 256;
    int r = idx >> 7, d = idx & 127;
    float s = sc[r * 128 + d] + sc[512 + r * 128 + d]
            + sc[1024 + r * 128 + d] + sc[1536 + r * 128 + d];
    pacc[(size_t)blk * 512 + r * 128 + d] = s;
  }
}

// ---- combine chunk partials; emit attn output as hi/lo bf16 (b-major) ----
__global__ __launch_bounds__(256) void combine_kernel(
    const float* __restrict__ pm, const float* __restrict__ pl,
    const float* __restrict__ pacc, unsigned short* __restrict__ ahi,
    unsigned short* __restrict__ alo) {
  int idx = blockIdx.x * 256 + threadIdx.x;
  int d = idx & 127, r = (idx >> 7) & 3, h = (idx >> 9) & 7, b = idx >> 12;
  int base = (b * 8 + h) * 8;
  float M = -1e30f;
#pragma unroll
  for (int c = 0; c < NCH; ++c) M = fmaxf(M, pm[(base + c) * 4 + r]);
  float num = 0.f, den = 0.f;
#pragma unroll
  for (int c = 0; c < NCH; ++c) {
    float w = __expf(pm[(base + c) * 4 + r] - M);
    den += w * pl[(base + c) * 4 + r];
    num += w * pacc[(size_t)(base + c) * 512 + r * 128 + d];
  }
  float val = num / den;
  int col = (h * 4 + r) * HD + d;
  unsigned short hh = f2bf(val);
  ahi[b * DIM + col] = hh;
  alo[b * DIM + col] = f2bf(val - bf2f(hh));
}

__global__ __launch_bounds__(256) void wo_reduce(
    const float* __restrict__ part, float* __restrict__ out) {
  int idx = blockIdx.x * 256 + threadIdx.x;
  int b = idx >> 11, c2 = idx & 2047;
  int c = c2 * 2;
  float s0 = 0.f, s1 = 0.f;
#pragma unroll
  for (int s = 0; s < QS; ++s) {
    float2 pv = *(const float2*)&part[((size_t)s * BATCH + b) * DIM + c];
    s0 += pv.x; s1 += pv.y;
  }
  out[b * DIM + c]     = s0;
  out[b * DIM + c + 1] = s1;
}

extern "C" void kernel_launch(void* const* d_in, const int* in_sizes, int n_in,
                              void* d_out, int out_size, void* d_ws, size_t ws_size,
                              hipStream_t stream) {
  const float* x  = (const float*)d_in[0];
  const float* wq = (const float*)d_in[1];
  const float* wk = (const float*)d_in[2];
  const float* wv = (const float*)d_in[3];
  const float* wo = (const float*)d_in[4];
  const float* ck = (const float*)d_in[5];
  const float* cv = (const float*)d_in[6];
  const float* fc = (const float*)d_in[7];
  const float* fs = (const float*)d_in[8];
  float* out = (float*)d_out;

  float* ws    = (float*)d_ws;
  float* ws_q  = ws;                 // 131072
  float* ws_k  = ws + 131072;        // 32768
  float* ws_v  = ws + 163840;        // 32768
  float* pm    = ws + 196608;        // 8192
  float* pl    = ws + 204800;        // 8192
  float* pacc  = ws + 212992;        // 1048576
  float* partq = ws + 1261568;       // 1572864 (8*32*6144)
  float* parto = ws + 2834432;       // 1048576 (8*32*4096)
  unsigned short* xhi = (unsigned short*)(ws + 3883008);   // 131072 u16
  unsigned short* xlo = (unsigned short*)(ws + 3948544);
  unsigned short* ahi = (unsigned short*)(ws + 4014080);
  unsigned short* alo = (unsigned short*)(ws + 4079616);
  // total ~4.15M floats ~= 16.6 MB

  cvt_hl<<<512, 256, 0, stream>>>(x, xhi, xlo, BATCH * DIM);
  gemm_qkv_mfma<<<dim3(96, QS), 256, 0, stream>>>(xhi, xlo, wq, wk, wv, partq);
  qkv_reduce_rope<<<384, 256, 0, stream>>>(partq, fc, fs, ws_q, ws_k, ws_v);

  attn_kernel<<<BATCH * NKV * NCH, 256, 0, stream>>>(ws_q, ck, cv, ws_k, ws_v, pm, pl, pacc);
  combine_kernel<<<512, 256, 0, stream>>>(pm, pl, pacc, ahi, alo);

  gemm_wo_mfma<<<dim3(64, QS), 256, 0, stream>>>(ahi, alo, wo, parto);
  wo_reduce<<<256, 256, 0, stream>>>(parto, out);
}

// Round 12
// 258.626 us; speedup vs baseline: 1.3374x; 1.0303x over previous
//
#include <hip/hip_runtime.h>
#include <hip/hip_bf16.h>

#define BATCH 32
#define DIM 4096
#define NH 32
#define NKV 8
#define HD 128
#define CTX 4096
#define NEWT 4095
#define CHUNK 512
#define NCH 8
#define QS 16                // k-split for MFMA GEMMs (k-span 256)
#define NQKV 6144
#define SM_SCALE 0.08838834764831845f  // 1/sqrt(128)

typedef __attribute__((ext_vector_type(8))) short bf16x8;
typedef __attribute__((ext_vector_type(4))) float f32x4;

__device__ inline unsigned short f2bf(float f) {
  union { __hip_bfloat16 h; unsigned short s; } u;
  u.h = __float2bfloat16(f);
  return u.s;
}
__device__ inline float bf2f(unsigned short s) {
  union { unsigned int u; float f; } v;
  v.u = ((unsigned int)s) << 16;
  return v.f;
}

// ---- fp32 -> (hi, lo) bf16 ----
__global__ __launch_bounds__(256) void cvt_hl(
    const float* __restrict__ src, unsigned short* __restrict__ hi,
    unsigned short* __restrict__ lo, int n) {
  int i = blockIdx.x * 256 + threadIdx.x;
  if (i < n) {
    float f = src[i];
    unsigned short h = f2bf(f);
    hi[i] = h;
    lo[i] = f2bf(f - bf2f(h));
  }
}

// ---- qkv GEMM: wave = 64 adjacent cols (4 tiles), A-frags reused ----
__global__ __launch_bounds__(256) void gemm_qkv_mfma(
    const unsigned short* __restrict__ xhi, const unsigned short* __restrict__ xlo,
    const float* __restrict__ wq, const float* __restrict__ wk,
    const float* __restrict__ wv, float* __restrict__ part) {
  int w = threadIdx.x >> 6, l = threadIdx.x & 63;
  int lc = l & 15, grp = l >> 4;
  int cb = (blockIdx.x * 4 + w) * 64;           // wave col base (0..6080)
  int sy = blockIdx.y;
  const float* W; int cwb, Nw;
  if (cb < 4096)      { W = wq; cwb = cb;        Nw = 4096; }
  else if (cb < 5120) { W = wk; cwb = cb - 4096; Nw = 1024; }
  else                { W = wv; cwb = cb - 5120; Nw = 1024; }
  const float* Wl = W + cwb + lc;               // lane's col in tile 0
  f32x4 acc0[4], acc1[4];
#pragma unroll
  for (int tt = 0; tt < 4; ++tt) {
    acc0[tt] = (f32x4){0.f, 0.f, 0.f, 0.f};
    acc1[tt] = (f32x4){0.f, 0.f, 0.f, 0.f};
  }
  for (int ks = 0; ks < 8; ++ks) {
    int ak = sy * 256 + ks * 32 + grp * 8;
    bf16x8 a0h = *(const bf16x8*)(xhi + (size_t)lc * DIM + ak);
    bf16x8 a0l = *(const bf16x8*)(xlo + (size_t)lc * DIM + ak);
    bf16x8 a1h = *(const bf16x8*)(xhi + (size_t)(16 + lc) * DIM + ak);
    bf16x8 a1l = *(const bf16x8*)(xlo + (size_t)(16 + lc) * DIM + ak);
#pragma unroll
    for (int tt = 0; tt < 4; ++tt) {
      const float* Wp = Wl + tt * 16 + (size_t)ak * Nw;
      float wvv[8];
#pragma unroll
      for (int j = 0; j < 8; ++j)
        wvv[j] = Wp[(size_t)j * Nw];
      bf16x8 bh, bl;
#pragma unroll
      for (int j = 0; j < 8; ++j) {
        unsigned short h = f2bf(wvv[j]);
        bh[j] = (short)h;
        bl[j] = (short)f2bf(wvv[j] - bf2f(h));
      }
      acc0[tt] = __builtin_amdgcn_mfma_f32_16x16x32_bf16(a0h, bh, acc0[tt], 0, 0, 0);
      acc0[tt] = __builtin_amdgcn_mfma_f32_16x16x32_bf16(a0h, bl, acc0[tt], 0, 0, 0);
      acc0[tt] = __builtin_amdgcn_mfma_f32_16x16x32_bf16(a0l, bh, acc0[tt], 0, 0, 0);
      acc1[tt] = __builtin_amdgcn_mfma_f32_16x16x32_bf16(a1h, bh, acc1[tt], 0, 0, 0);
      acc1[tt] = __builtin_amdgcn_mfma_f32_16x16x32_bf16(a1h, bl, acc1[tt], 0, 0, 0);
      acc1[tt] = __builtin_amdgcn_mfma_f32_16x16x32_bf16(a1l, bh, acc1[tt], 0, 0, 0);
    }
  }
#pragma unroll
  for (int tt = 0; tt < 4; ++tt) {
    int c = cb + tt * 16 + lc;
#pragma unroll
    for (int i = 0; i < 4; ++i) {
      int b0 = grp * 4 + i;
      part[((size_t)sy * BATCH + b0) * NQKV + c] = acc0[tt][i];
      part[((size_t)sy * BATCH + 16 + b0) * NQKV + c] = acc1[tt][i];
    }
  }
}

// ---- wo GEMM, same scheme ----
__global__ __launch_bounds__(256) void gemm_wo_mfma(
    const unsigned short* __restrict__ ahi, const unsigned short* __restrict__ alo,
    const float* __restrict__ W, float* __restrict__ part) {
  int w = threadIdx.x >> 6, l = threadIdx.x & 63;
  int lc = l & 15, grp = l >> 4;
  int cb = (blockIdx.x * 4 + w) * 64;           // 0..4032
  int sy = blockIdx.y;
  const float* Wl = W + cb + lc;
  f32x4 acc0[4], acc1[4];
#pragma unroll
  for (int tt = 0; tt < 4; ++tt) {
    acc0[tt] = (f32x4){0.f, 0.f, 0.f, 0.f};
    acc1[tt] = (f32x4){0.f, 0.f, 0.f, 0.f};
  }
  for (int ks = 0; ks < 8; ++ks) {
    int ak = sy * 256 + ks * 32 + grp * 8;
    bf16x8 a0h = *(const bf16x8*)(ahi + (size_t)lc * DIM + ak);
    bf16x8 a0l = *(const bf16x8*)(alo + (size_t)lc * DIM + ak);
    bf16x8 a1h = *(const bf16x8*)(ahi + (size_t)(16 + lc) * DIM + ak);
    bf16x8 a1l = *(const bf16x8*)(alo + (size_t)(16 + lc) * DIM + ak);
#pragma unroll
    for (int tt = 0; tt < 4; ++tt) {
      const float* Wp = Wl + tt * 16 + (size_t)ak * DIM;
      float wvv[8];
#pragma unroll
      for (int j = 0; j < 8; ++j)
        wvv[j] = Wp[(size_t)j * DIM];
      bf16x8 bh, bl;
#pragma unroll
      for (int j = 0; j < 8; ++j) {
        unsigned short h = f2bf(wvv[j]);
        bh[j] = (short)h;
        bl[j] = (short)f2bf(wvv[j] - bf2f(h));
      }
      acc0[tt] = __builtin_amdgcn_mfma_f32_16x16x32_bf16(a0h, bh, acc0[tt], 0, 0, 0);
      acc0[tt] = __builtin_amdgcn_mfma_f32_16x16x32_bf16(a0h, bl, acc0[tt], 0, 0, 0);
      acc0[tt] = __builtin_amdgcn_mfma_f32_16x16x32_bf16(a0l, bh, acc0[tt], 0, 0, 0);
      acc1[tt] = __builtin_amdgcn_mfma_f32_16x16x32_bf16(a1h, bh, acc1[tt], 0, 0, 0);
      acc1[tt] = __builtin_amdgcn_mfma_f32_16x16x32_bf16(a1h, bl, acc1[tt], 0, 0, 0);
      acc1[tt] = __builtin_amdgcn_mfma_f32_16x16x32_bf16(a1l, bh, acc1[tt], 0, 0, 0);
    }
  }
#pragma unroll
  for (int tt = 0; tt < 4; ++tt) {
    int c = cb + tt * 16 + lc;
#pragma unroll
    for (int i = 0; i < 4; ++i) {
      int b0 = grp * 4 + i;
      part[((size_t)sy * BATCH + b0) * DIM + c] = acc0[tt][i];
      part[((size_t)sy * BATCH + 16 + b0) * DIM + c] = acc1[tt][i];
    }
  }
}

// ---- reduce qkv partials + RoPE ----
__global__ __launch_bounds__(256) void qkv_reduce_rope(
    const float* __restrict__ part, const float* __restrict__ cos_t,
    const float* __restrict__ sin_t, float* __restrict__ q,
    float* __restrict__ k, float* __restrict__ v) {
  int idx = blockIdx.x * 256 + threadIdx.x;
  int b = idx / 3072, c2 = idx - b * 3072;
  int c = c2 * 2;
  float s0 = 0.f, s1 = 0.f;
#pragma unroll 8
  for (int s = 0; s < QS; ++s) {
    float2 pv = *(const float2*)&part[((size_t)s * BATCH + b) * NQKV + c];
    s0 += pv.x; s1 += pv.y;
  }
  if (c < 4096) {
    int p = (c & 127) >> 1;
    float cc = cos_t[p], ss = sin_t[p];
    q[b * 4096 + c]     = s0 * cc - s1 * ss;
    q[b * 4096 + c + 1] = s0 * ss + s1 * cc;
  } else if (c < 5120) {
    int c0 = c - 4096;
    int p = (c0 & 127) >> 1;
    float cc = cos_t[p], ss = sin_t[p];
    k[b * 1024 + c0]     = s0 * cc - s1 * ss;
    k[b * 1024 + c0 + 1] = s0 * ss + s1 * cc;
  } else {
    int c0 = c - 5120;
    v[b * 1024 + c0]     = s0;
    v[b * 1024 + c0 + 1] = s1;
  }
}

// ---- flash-decode partial (R3-proven) ----
__global__ __launch_bounds__(256, 2) void attn_kernel(
    const float* __restrict__ q,
    const float* __restrict__ kcache,
    const float* __restrict__ vcache,
    const float* __restrict__ knew,
    const float* __restrict__ vnew,
    float* __restrict__ pm, float* __restrict__ pl,
    float* __restrict__ pacc) {
  __shared__ float sc[4 * CHUNK];
  __shared__ float sml[8];
  int blk = blockIdx.x;
  int c = blk & 7, h = (blk >> 3) & 7, b = blk >> 6;
  int tid = threadIdx.x;
  int wave = tid >> 6, sub = tid & 63;
  int t_base = c * CHUNK;

  int tg = tid >> 4;
  int lig = tid & 15;
  float qreg[4][8];
#pragma unroll
  for (int r = 0; r < 4; ++r)
#pragma unroll
    for (int j = 0; j < 8; ++j)
      qreg[r][j] = q[b * (NH * HD) + (h * 4 + r) * HD + lig * 8 + j];

  const float* kbase = kcache + ((size_t)b * CTX * NKV + h) * HD;
  const float* knrow = knew + (b * NKV + h) * HD;
  for (int t0 = 0; t0 < CHUNK; t0 += 16) {
    int tl = t0 + tg;
    int t = t_base + tl;
    const float* krow = (t < NEWT) ? (kbase + (size_t)t * (NKV * HD)) : knrow;
    float4 ka = *(const float4*)(krow + lig * 8);
    float4 kb = *(const float4*)(krow + lig * 8 + 4);
#pragma unroll
    for (int r = 0; r < 4; ++r) {
      float part = ka.x * qreg[r][0] + ka.y * qreg[r][1] + ka.z * qreg[r][2] + ka.w * qreg[r][3]
                 + kb.x * qreg[r][4] + kb.y * qreg[r][5] + kb.z * qreg[r][6] + kb.w * qreg[r][7];
#pragma unroll
      for (int off = 8; off >= 1; off >>= 1)
        part += __shfl_xor(part, off);
      if (lig == 0) sc[r * CHUNK + tl] = part * SM_SCALE;
    }
  }
  __syncthreads();

  {
    int r = wave;
    float m = -1e30f;
    for (int i = sub; i < CHUNK; i += 64) m = fmaxf(m, sc[r * CHUNK + i]);
#pragma unroll
    for (int off = 32; off >= 1; off >>= 1) m = fmaxf(m, __shfl_xor(m, off));
    float ssum = 0.f;
    for (int i = sub; i < CHUNK; i += 64) {
      float pv = __expf(sc[r * CHUNK + i] - m);
      sc[r * CHUNK + i] = pv;
      ssum += pv;
    }
#pragma unroll
    for (int off = 32; off >= 1; off >>= 1) ssum += __shfl_xor(ssum, off);
    if (sub == 0) { sml[r] = m; sml[4 + r] = ssum; }
  }
  __syncthreads();
  if (tid < 4) {
    pm[blk * 4 + tid] = sml[tid];
    pl[blk * 4 + tid] = sml[4 + tid];
  }

  int dg = tid & 31;
  int tg2 = tid >> 5;
  float4 acc[4];
#pragma unroll
  for (int r = 0; r < 4; ++r) acc[r] = make_float4(0.f, 0.f, 0.f, 0.f);
  const float* vbase = vcache + ((size_t)b * CTX * NKV + h) * HD;
  const float* vnrow = vnew + (b * NKV + h) * HD;
  for (int t0 = 0; t0 < CHUNK; t0 += 16) {
    int tla = t0 + tg2, tlb = t0 + tg2 + 8;
    int ta = t_base + tla, tb = t_base + tlb;
    const float* vra = (ta < NEWT) ? (vbase + (size_t)ta * (NKV * HD)) : vnrow;
    const float* vrb = (tb < NEWT) ? (vbase + (size_t)tb * (NKV * HD)) : vnrow;
    float4 va = *(const float4*)(vra + dg * 4);
    float4 vb = *(const float4*)(vrb + dg * 4);
#pragma unroll
    for (int r = 0; r < 4; ++r) {
      float pa = sc[r * CHUNK + tla];
      float pb = sc[r * CHUNK + tlb];
      acc[r].x += pa * va.x + pb * vb.x;
      acc[r].y += pa * va.y + pb * vb.y;
      acc[r].z += pa * va.z + pb * vb.z;
      acc[r].w += pa * va.w + pb * vb.w;
    }
  }
#pragma unroll
  for (int r = 0; r < 4; ++r) {
    acc[r].x += __shfl_xor(acc[r].x, 32);
    acc[r].y += __shfl_xor(acc[r].y, 32);
    acc[r].z += __shfl_xor(acc[r].z, 32);
    acc[r].w += __shfl_xor(acc[r].w, 32);
  }
  __syncthreads();
  if (sub < 32) {
#pragma unroll
    for (int r = 0; r < 4; ++r)
      *(float4*)&sc[wave * 512 + r * 128 + dg * 4] = acc[r];
  }
  __syncthreads();
#pragma unroll
  for (int rr = 0; rr < 2; ++rr) {
    int idx = tid + rr * 256;
    int r = idx >> 7, d = idx & 127;
    float s = sc[r * 128 + d] + sc[512 + r * 128 + d]
            + sc[1024 + r * 128 + d] + sc[1536 + r * 128 + d];
    pacc[(size_t)blk * 512 + r * 128 + d] = s;
  }
}

// ---- combine chunk partials; emit attn output as hi/lo bf16 ----
__global__ __launch_bounds__(256) void combine_kernel(
    const float* __restrict__ pm, const float* __restrict__ pl,
    const float* __restrict__ pacc, unsigned short* __restrict__ ahi,
    unsigned short* __restrict__ alo) {
  int idx = blockIdx.x * 256 + threadIdx.x;
  int d = idx & 127, r = (idx >> 7) & 3, h = (idx >> 9) & 7, b = idx >> 12;
  int base = (b * 8 + h) * 8;
  float M = -1e30f;
#pragma unroll
  for (int c = 0; c < NCH; ++c) M = fmaxf(M, pm[(base + c) * 4 + r]);
  float num = 0.f, den = 0.f;
#pragma unroll
  for (int c = 0; c < NCH; ++c) {
    float w = __expf(pm[(base + c) * 4 + r] - M);
    den += w * pl[(base + c) * 4 + r];
    num += w * pacc[(size_t)(base + c) * 512 + r * 128 + d];
  }
  float val = num / den;
  int col = (h * 4 + r) * HD + d;
  unsigned short hh = f2bf(val);
  ahi[b * DIM + col] = hh;
  alo[b * DIM + col] = f2bf(val - bf2f(hh));
}

__global__ __launch_bounds__(256) void wo_reduce(
    const float* __restrict__ part, float* __restrict__ out) {
  int idx = blockIdx.x * 256 + threadIdx.x;
  int b = idx >> 11, c2 = idx & 2047;
  int c = c2 * 2;
  float s0 = 0.f, s1 = 0.f;
#pragma unroll 8
  for (int s = 0; s < QS; ++s) {
    float2 pv = *(const float2*)&part[((size_t)s * BATCH + b) * DIM + c];
    s0 += pv.x; s1 += pv.y;
  }
  out[b * DIM + c]     = s0;
  out[b * DIM + c + 1] = s1;
}

extern "C" void kernel_launch(void* const* d_in, const int* in_sizes, int n_in,
                              void* d_out, int out_size, void* d_ws, size_t ws_size,
                              hipStream_t stream) {
  const float* x  = (const float*)d_in[0];
  const float* wq = (const float*)d_in[1];
  const float* wk = (const float*)d_in[2];
  const float* wv = (const float*)d_in[3];
  const float* wo = (const float*)d_in[4];
  const float* ck = (const float*)d_in[5];
  const float* cv = (const float*)d_in[6];
  const float* fc = (const float*)d_in[7];
  const float* fs = (const float*)d_in[8];
  float* out = (float*)d_out;

  float* ws    = (float*)d_ws;
  float* ws_q  = ws;                 // 131072
  float* ws_k  = ws + 131072;        // 32768
  float* ws_v  = ws + 163840;        // 32768
  float* pm    = ws + 196608;        // 8192
  float* pl    = ws + 204800;        // 8192
  float* pacc  = ws + 212992;        // 1048576
  float* partq = ws + 1261568;       // 3145728 (16*32*6144)
  float* parto = ws + 4407296;       // 2097152 (16*32*4096)
  unsigned short* xhi = (unsigned short*)(ws + 6504448);   // 131072 u16
  unsigned short* xlo = (unsigned short*)(ws + 6569984);
  unsigned short* ahi = (unsigned short*)(ws + 6635520);
  unsigned short* alo = (unsigned short*)(ws + 6701056);
  // total ~6.77M floats ~= 27 MB

  cvt_hl<<<512, 256, 0, stream>>>(x, xhi, xlo, BATCH * DIM);
  gemm_qkv_mfma<<<dim3(24, QS), 256, 0, stream>>>(xhi, xlo, wq, wk, wv, partq);
  qkv_reduce_rope<<<384, 256, 0, stream>>>(partq, fc, fs, ws_q, ws_k, ws_v);

  attn_kernel<<<BATCH * NKV * NCH, 256, 0, stream>>>(ws_q, ck, cv, ws_k, ws_v, pm, pl, pacc);
  combine_kernel<<<512, 256, 0, stream>>>(pm, pl, pacc, ahi, alo);

  gemm_wo_mfma<<<dim3(16, QS), 256, 0, stream>>>(ahi, alo, wo, parto);
  wo_reduce<<<256, 256, 0, stream>>>(parto, out);
}

// Round 13
// 257.952 us; speedup vs baseline: 1.3409x; 1.0026x over previous
//
#include <hip/hip_runtime.h>
#include <hip/hip_bf16.h>

#define BATCH 32
#define DIM 4096
#define NH 32
#define NKV 8
#define HD 128
#define CTX 4096
#define NEWT 4095
#define CHUNK 512
#define NCH 8
#define QS 16                // k-split for MFMA GEMMs (k-span 256)
#define NQKV 6144
#define SM_SCALE 0.08838834764831845f  // 1/sqrt(128)

typedef __attribute__((ext_vector_type(8))) short bf16x8;
typedef __attribute__((ext_vector_type(4))) float f32x4;

__device__ inline unsigned short f2bf(float f) {
  union { __hip_bfloat16 h; unsigned short s; } u;
  u.h = __float2bfloat16(f);
  return u.s;
}
__device__ inline float bf2f(unsigned short s) {
  union { unsigned int u; float f; } v;
  v.u = ((unsigned int)s) << 16;
  return v.f;
}
__device__ inline void split8(float4 a, float4 b, bf16x8& h8, bf16x8& l8) {
  float f[8] = {a.x, a.y, a.z, a.w, b.x, b.y, b.z, b.w};
#pragma unroll
  for (int j = 0; j < 8; ++j) {
    unsigned short h = f2bf(f[j]);
    h8[j] = (short)h;
    l8[j] = (short)f2bf(f[j] - bf2f(h));
  }
}

// ---- qkv GEMM: wave = 64 adjacent cols (4 tiles); fp32 A, in-reg hi/lo split ----
__global__ __launch_bounds__(256) void gemm_qkv_mfma(
    const float* __restrict__ x,
    const float* __restrict__ wq, const float* __restrict__ wk,
    const float* __restrict__ wv, float* __restrict__ part) {
  int w = threadIdx.x >> 6, l = threadIdx.x & 63;
  int lc = l & 15, grp = l >> 4;
  int cb = (blockIdx.x * 4 + w) * 64;           // wave col base (0..6080)
  int sy = blockIdx.y;
  const float* W; int cwb, Nw;
  if (cb < 4096)      { W = wq; cwb = cb;        Nw = 4096; }
  else if (cb < 5120) { W = wk; cwb = cb - 4096; Nw = 1024; }
  else                { W = wv; cwb = cb - 5120; Nw = 1024; }
  const float* Wl = W + cwb + lc;               // lane's col in tile 0
  f32x4 acc0[4], acc1[4];
#pragma unroll
  for (int tt = 0; tt < 4; ++tt) {
    acc0[tt] = (f32x4){0.f, 0.f, 0.f, 0.f};
    acc1[tt] = (f32x4){0.f, 0.f, 0.f, 0.f};
  }
  for (int ks = 0; ks < 8; ++ks) {
    int ak = sy * 256 + ks * 32 + grp * 8;
    const float* xr0 = x + (size_t)lc * DIM + ak;
    const float* xr1 = x + (size_t)(16 + lc) * DIM + ak;
    float4 f0a = *(const float4*)xr0, f0b = *(const float4*)(xr0 + 4);
    float4 f1a = *(const float4*)xr1, f1b = *(const float4*)(xr1 + 4);
    bf16x8 a0h, a0l, a1h, a1l;
    split8(f0a, f0b, a0h, a0l);
    split8(f1a, f1b, a1h, a1l);
#pragma unroll
    for (int tt = 0; tt < 4; ++tt) {
      const float* Wp = Wl + tt * 16 + (size_t)ak * Nw;
      float wvv[8];
#pragma unroll
      for (int j = 0; j < 8; ++j)
        wvv[j] = Wp[(size_t)j * Nw];
      bf16x8 bh, bl;
#pragma unroll
      for (int j = 0; j < 8; ++j) {
        unsigned short h = f2bf(wvv[j]);
        bh[j] = (short)h;
        bl[j] = (short)f2bf(wvv[j] - bf2f(h));
      }
      acc0[tt] = __builtin_amdgcn_mfma_f32_16x16x32_bf16(a0h, bh, acc0[tt], 0, 0, 0);
      acc0[tt] = __builtin_amdgcn_mfma_f32_16x16x32_bf16(a0h, bl, acc0[tt], 0, 0, 0);
      acc0[tt] = __builtin_amdgcn_mfma_f32_16x16x32_bf16(a0l, bh, acc0[tt], 0, 0, 0);
      acc1[tt] = __builtin_amdgcn_mfma_f32_16x16x32_bf16(a1h, bh, acc1[tt], 0, 0, 0);
      acc1[tt] = __builtin_amdgcn_mfma_f32_16x16x32_bf16(a1h, bl, acc1[tt], 0, 0, 0);
      acc1[tt] = __builtin_amdgcn_mfma_f32_16x16x32_bf16(a1l, bh, acc1[tt], 0, 0, 0);
    }
  }
#pragma unroll
  for (int tt = 0; tt < 4; ++tt) {
    int c = cb + tt * 16 + lc;
#pragma unroll
    for (int i = 0; i < 4; ++i) {
      int b0 = grp * 4 + i;
      part[((size_t)sy * BATCH + b0) * NQKV + c] = acc0[tt][i];
      part[((size_t)sy * BATCH + 16 + b0) * NQKV + c] = acc1[tt][i];
    }
  }
}

// ---- wo GEMM: A pre-split by combine (hi/lo bf16) ----
__global__ __launch_bounds__(256) void gemm_wo_mfma(
    const unsigned short* __restrict__ ahi, const unsigned short* __restrict__ alo,
    const float* __restrict__ W, float* __restrict__ part) {
  int w = threadIdx.x >> 6, l = threadIdx.x & 63;
  int lc = l & 15, grp = l >> 4;
  int cb = (blockIdx.x * 4 + w) * 64;           // 0..4032
  int sy = blockIdx.y;
  const float* Wl = W + cb + lc;
  f32x4 acc0[4], acc1[4];
#pragma unroll
  for (int tt = 0; tt < 4; ++tt) {
    acc0[tt] = (f32x4){0.f, 0.f, 0.f, 0.f};
    acc1[tt] = (f32x4){0.f, 0.f, 0.f, 0.f};
  }
  for (int ks = 0; ks < 8; ++ks) {
    int ak = sy * 256 + ks * 32 + grp * 8;
    bf16x8 a0h = *(const bf16x8*)(ahi + (size_t)lc * DIM + ak);
    bf16x8 a0l = *(const bf16x8*)(alo + (size_t)lc * DIM + ak);
    bf16x8 a1h = *(const bf16x8*)(ahi + (size_t)(16 + lc) * DIM + ak);
    bf16x8 a1l = *(const bf16x8*)(alo + (size_t)(16 + lc) * DIM + ak);
#pragma unroll
    for (int tt = 0; tt < 4; ++tt) {
      const float* Wp = Wl + tt * 16 + (size_t)ak * DIM;
      float wvv[8];
#pragma unroll
      for (int j = 0; j < 8; ++j)
        wvv[j] = Wp[(size_t)j * DIM];
      bf16x8 bh, bl;
#pragma unroll
      for (int j = 0; j < 8; ++j) {
        unsigned short h = f2bf(wvv[j]);
        bh[j] = (short)h;
        bl[j] = (short)f2bf(wvv[j] - bf2f(h));
      }
      acc0[tt] = __builtin_amdgcn_mfma_f32_16x16x32_bf16(a0h, bh, acc0[tt], 0, 0, 0);
      acc0[tt] = __builtin_amdgcn_mfma_f32_16x16x32_bf16(a0h, bl, acc0[tt], 0, 0, 0);
      acc0[tt] = __builtin_amdgcn_mfma_f32_16x16x32_bf16(a0l, bh, acc0[tt], 0, 0, 0);
      acc1[tt] = __builtin_amdgcn_mfma_f32_16x16x32_bf16(a1h, bh, acc1[tt], 0, 0, 0);
      acc1[tt] = __builtin_amdgcn_mfma_f32_16x16x32_bf16(a1h, bl, acc1[tt], 0, 0, 0);
      acc1[tt] = __builtin_amdgcn_mfma_f32_16x16x32_bf16(a1l, bh, acc1[tt], 0, 0, 0);
    }
  }
#pragma unroll
  for (int tt = 0; tt < 4; ++tt) {
    int c = cb + tt * 16 + lc;
#pragma unroll
    for (int i = 0; i < 4; ++i) {
      int b0 = grp * 4 + i;
      part[((size_t)sy * BATCH + b0) * DIM + c] = acc0[tt][i];
      part[((size_t)sy * BATCH + 16 + b0) * DIM + c] = acc1[tt][i];
    }
  }
}

// ---- reduce qkv partials + RoPE ----
__global__ __launch_bounds__(256) void qkv_reduce_rope(
    const float* __restrict__ part, const float* __restrict__ cos_t,
    const float* __restrict__ sin_t, float* __restrict__ q,
    float* __restrict__ k, float* __restrict__ v) {
  int idx = blockIdx.x * 256 + threadIdx.x;
  int b = idx / 3072, c2 = idx - b * 3072;
  int c = c2 * 2;
  float s0 = 0.f, s1 = 0.f;
#pragma unroll 8
  for (int s = 0; s < QS; ++s) {
    float2 pv = *(const float2*)&part[((size_t)s * BATCH + b) * NQKV + c];
    s0 += pv.x; s1 += pv.y;
  }
  if (c < 4096) {
    int p = (c & 127) >> 1;
    float cc = cos_t[p], ss = sin_t[p];
    q[b * 4096 + c]     = s0 * cc - s1 * ss;
    q[b * 4096 + c + 1] = s0 * ss + s1 * cc;
  } else if (c < 5120) {
    int c0 = c - 4096;
    int p = (c0 & 127) >> 1;
    float cc = cos_t[p], ss = sin_t[p];
    k[b * 1024 + c0]     = s0 * cc - s1 * ss;
    k[b * 1024 + c0 + 1] = s0 * ss + s1 * cc;
  } else {
    int c0 = c - 5120;
    v[b * 1024 + c0]     = s0;
    v[b * 1024 + c0 + 1] = s1;
  }
}

// ---- flash-decode partial (R3-proven) ----
__global__ __launch_bounds__(256, 2) void attn_kernel(
    const float* __restrict__ q,
    const float* __restrict__ kcache,
    const float* __restrict__ vcache,
    const float* __restrict__ knew,
    const float* __restrict__ vnew,
    float* __restrict__ pm, float* __restrict__ pl,
    float* __restrict__ pacc) {
  __shared__ float sc[4 * CHUNK];
  __shared__ float sml[8];
  int blk = blockIdx.x;
  int c = blk & 7, h = (blk >> 3) & 7, b = blk >> 6;
  int tid = threadIdx.x;
  int wave = tid >> 6, sub = tid & 63;
  int t_base = c * CHUNK;

  int tg = tid >> 4;
  int lig = tid & 15;
  float qreg[4][8];
#pragma unroll
  for (int r = 0; r < 4; ++r)
#pragma unroll
    for (int j = 0; j < 8; ++j)
      qreg[r][j] = q[b * (NH * HD) + (h * 4 + r) * HD + lig * 8 + j];

  const float* kbase = kcache + ((size_t)b * CTX * NKV + h) * HD;
  const float* knrow = knew + (b * NKV + h) * HD;
  for (int t0 = 0; t0 < CHUNK; t0 += 16) {
    int tl = t0 + tg;
    int t = t_base + tl;
    const float* krow = (t < NEWT) ? (kbase + (size_t)t * (NKV * HD)) : knrow;
    float4 ka = *(const float4*)(krow + lig * 8);
    float4 kb = *(const float4*)(krow + lig * 8 + 4);
#pragma unroll
    for (int r = 0; r < 4; ++r) {
      float part = ka.x * qreg[r][0] + ka.y * qreg[r][1] + ka.z * qreg[r][2] + ka.w * qreg[r][3]
                 + kb.x * qreg[r][4] + kb.y * qreg[r][5] + kb.z * qreg[r][6] + kb.w * qreg[r][7];
#pragma unroll
      for (int off = 8; off >= 1; off >>= 1)
        part += __shfl_xor(part, off);
      if (lig == 0) sc[r * CHUNK + tl] = part * SM_SCALE;
    }
  }
  __syncthreads();

  {
    int r = wave;
    float m = -1e30f;
    for (int i = sub; i < CHUNK; i += 64) m = fmaxf(m, sc[r * CHUNK + i]);
#pragma unroll
    for (int off = 32; off >= 1; off >>= 1) m = fmaxf(m, __shfl_xor(m, off));
    float ssum = 0.f;
    for (int i = sub; i < CHUNK; i += 64) {
      float pv = __expf(sc[r * CHUNK + i] - m);
      sc[r * CHUNK + i] = pv;
      ssum += pv;
    }
#pragma unroll
    for (int off = 32; off >= 1; off >>= 1) ssum += __shfl_xor(ssum, off);
    if (sub == 0) { sml[r] = m; sml[4 + r] = ssum; }
  }
  __syncthreads();
  if (tid < 4) {
    pm[blk * 4 + tid] = sml[tid];
    pl[blk * 4 + tid] = sml[4 + tid];
  }

  int dg = tid & 31;
  int tg2 = tid >> 5;
  float4 acc[4];
#pragma unroll
  for (int r = 0; r < 4; ++r) acc[r] = make_float4(0.f, 0.f, 0.f, 0.f);
  const float* vbase = vcache + ((size_t)b * CTX * NKV + h) * HD;
  const float* vnrow = vnew + (b * NKV + h) * HD;
  for (int t0 = 0; t0 < CHUNK; t0 += 16) {
    int tla = t0 + tg2, tlb = t0 + tg2 + 8;
    int ta = t_base + tla, tb = t_base + tlb;
    const float* vra = (ta < NEWT) ? (vbase + (size_t)ta * (NKV * HD)) : vnrow;
    const float* vrb = (tb < NEWT) ? (vbase + (size_t)tb * (NKV * HD)) : vnrow;
    float4 va = *(const float4*)(vra + dg * 4);
    float4 vb = *(const float4*)(vrb + dg * 4);
#pragma unroll
    for (int r = 0; r < 4; ++r) {
      float pa = sc[r * CHUNK + tla];
      float pb = sc[r * CHUNK + tlb];
      acc[r].x += pa * va.x + pb * vb.x;
      acc[r].y += pa * va.y + pb * vb.y;
      acc[r].z += pa * va.z + pb * vb.z;
      acc[r].w += pa * va.w + pb * vb.w;
    }
  }
#pragma unroll
  for (int r = 0; r < 4; ++r) {
    acc[r].x += __shfl_xor(acc[r].x, 32);
    acc[r].y += __shfl_xor(acc[r].y, 32);
    acc[r].z += __shfl_xor(acc[r].z, 32);
    acc[r].w += __shfl_xor(acc[r].w, 32);
  }
  __syncthreads();
  if (sub < 32) {
#pragma unroll
    for (int r = 0; r < 4; ++r)
      *(float4*)&sc[wave * 512 + r * 128 + dg * 4] = acc[r];
  }
  __syncthreads();
#pragma unroll
  for (int rr = 0; rr < 2; ++rr) {
    int idx = tid + rr * 256;
    int r = idx >> 7, d = idx & 127;
    float s = sc[r * 128 + d] + sc[512 + r * 128 + d]
            + sc[1024 + r * 128 + d] + sc[1536 + r * 128 + d];
    pacc[(size_t)blk * 512 + r * 128 + d] = s;
  }
}

// ---- combine chunk partials; emit attn output as hi/lo bf16 ----
__global__ __launch_bounds__(256) void combine_kernel(
    const float* __restrict__ pm, const float* __restrict__ pl,
    const float* __restrict__ pacc, unsigned short* __restrict__ ahi,
    unsigned short* __restrict__ alo) {
  int idx = blockIdx.x * 256 + threadIdx.x;
  int d = idx & 127, r = (idx >> 7) & 3, h = (idx >> 9) & 7, b = idx >> 12;
  int base = (b * 8 + h) * 8;
  float M = -1e30f;
#pragma unroll
  for (int c = 0; c < NCH; ++c) M = fmaxf(M, pm[(base + c) * 4 + r]);
  float num = 0.f, den = 0.f;
#pragma unroll
  for (int c = 0; c < NCH; ++c) {
    float w = __expf(pm[(base + c) * 4 + r] - M);
    den += w * pl[(base + c) * 4 + r];
    num += w * pacc[(size_t)(base + c) * 512 + r * 128 + d];
  }
  float val = num / den;
  int col = (h * 4 + r) * HD + d;
  unsigned short hh = f2bf(val);
  ahi[b * DIM + col] = hh;
  alo[b * DIM + col] = f2bf(val - bf2f(hh));
}

__global__ __launch_bounds__(256) void wo_reduce(
    const float* __restrict__ part, float* __restrict__ out) {
  int idx = blockIdx.x * 256 + threadIdx.x;
  int b = idx >> 11, c2 = idx & 2047;
  int c = c2 * 2;
  float s0 = 0.f, s1 = 0.f;
#pragma unroll 8
  for (int s = 0; s < QS; ++s) {
    float2 pv = *(const float2*)&part[((size_t)s * BATCH + b) * DIM + c];
    s0 += pv.x; s1 += pv.y;
  }
  out[b * DIM + c]     = s0;
  out[b * DIM + c + 1] = s1;
}

extern "C" void kernel_launch(void* const* d_in, const int* in_sizes, int n_in,
                              void* d_out, int out_size, void* d_ws, size_t ws_size,
                              hipStream_t stream) {
  const float* x  = (const float*)d_in[0];
  const float* wq = (const float*)d_in[1];
  const float* wk = (const float*)d_in[2];
  const float* wv = (const float*)d_in[3];
  const float* wo = (const float*)d_in[4];
  const float* ck = (const float*)d_in[5];
  const float* cv = (const float*)d_in[6];
  const float* fc = (const float*)d_in[7];
  const float* fs = (const float*)d_in[8];
  float* out = (float*)d_out;

  float* ws    = (float*)d_ws;
  float* ws_q  = ws;                 // 131072
  float* ws_k  = ws + 131072;        // 32768
  float* ws_v  = ws + 163840;        // 32768
  float* pm    = ws + 196608;        // 8192
  float* pl    = ws + 204800;        // 8192
  float* pacc  = ws + 212992;        // 1048576
  float* partq = ws + 1261568;       // 3145728 (16*32*6144)
  float* parto = ws + 4407296;       // 2097152 (16*32*4096)
  unsigned short* ahi = (unsigned short*)(ws + 6504448);   // 131072 u16
  unsigned short* alo = (unsigned short*)(ws + 6569984);
  // total ~6.64M floats ~= 26.6 MB

  gemm_qkv_mfma<<<dim3(24, QS), 256, 0, stream>>>(x, wq, wk, wv, partq);
  qkv_reduce_rope<<<384, 256, 0, stream>>>(partq, fc, fs, ws_q, ws_k, ws_v);

  attn_kernel<<<BATCH * NKV * NCH, 256, 0, stream>>>(ws_q, ck, cv, ws_k, ws_v, pm, pl, pacc);
  combine_kernel<<<512, 256, 0, stream>>>(pm, pl, pacc, ahi, alo);

  gemm_wo_mfma<<<dim3(16, QS), 256, 0, stream>>>(ahi, alo, wo, parto);
  wo_reduce<<<256, 256, 0, stream>>>(parto, out);
}